// Round 1
// baseline (4973.141 us; speedup 1.0000x reference)
//
#include <hip/hip_runtime.h>

// LSTM_48850958024796: bidirectional 2-layer LSTM + FC + softmax, fp32 baseline.
// B=1024, T=128, IN=5, H=100. Key algorithmic facts:
//  - batch-parallel recurrence: each block owns RB batch rows, loops t in-kernel
//  - layer-1 backward contributes ONLY its t=T-1 output = first reverse step
//    (h=c=0, input h0[:,T-1,:]) -> single cell step, fused into lstm_l1
//  - weights pre-packed to [K/4][G] float4 so lanes (gate-contiguous) read
//    coalesced 16B; h/x staged in LDS, read as wave-broadcast (conflict-free)

constexpr int Bsz = 1024;
constexpr int Tt  = 128;
constexpr int IN  = 5;
constexpr int H   = 100;
constexpr int G   = 400;   // 4*H, gate order i,f,g,o
constexpr int D1  = 200;   // 2*H
constexpr int RB  = 8;     // batch rows per block

__device__ __forceinline__ float sigm(float x)   { return 1.f / (1.f + __expf(-x)); }
__device__ __forceinline__ float tanh_f(float x) { return 1.f - 2.f / (__expf(2.f * x) + 1.f); }

// repack W[g][k] (row-major, K%4==0) -> pk[kc][g] as float4 = W[g][4kc..4kc+3]
__global__ void pack_w(const float* __restrict__ src, float* __restrict__ dst, int GG, int K) {
  int idx = blockIdx.x * blockDim.x + threadIdx.x;
  if (idx >= GG * K) return;
  int g = idx / K, k = idx - g * K;
  dst[(((k >> 2) * GG + g) << 2) + (k & 3)] = src[idx];
}

// ---------------- layer 0, both directions (grid.y = dir) ----------------
__global__ __launch_bounds__(256) void lstm_l0(
    const float* __restrict__ x,
    const float* __restrict__ wih_f, const float* __restrict__ bih_f, const float* __restrict__ bhh_f,
    const float* __restrict__ wih_b, const float* __restrict__ bih_b, const float* __restrict__ bhh_b,
    const float4* __restrict__ pk_f, const float4* __restrict__ pk_b,
    float* __restrict__ h0)
{
  __shared__ float  wih_s[G * IN];
  __shared__ float  bias_s[G];
  __shared__ float4 h4[RB][H / 4];      // h state, rows contiguous (100 floats)
  __shared__ float  c_s[RB][H];
  __shared__ float  gbuf[RB][G];
  __shared__ float  x_s[RB][IN];

  const int tid = threadIdx.x;
  const int b0  = blockIdx.x * RB;
  const int dir = blockIdx.y;
  const float*  wih = dir ? wih_b : wih_f;
  const float*  bih = dir ? bih_b : bih_f;
  const float*  bhh = dir ? bhh_b : bhh_f;
  const float4* pk  = dir ? pk_b  : pk_f;
  float* hrow = (float*)h4;

  for (int i = tid; i < G * IN; i += 256) wih_s[i] = wih[i];
  for (int i = tid; i < G; i += 256)      bias_s[i] = bih[i] + bhh[i];
  for (int i = tid; i < RB * H; i += 256) { hrow[i] = 0.f; (&c_s[0][0])[i] = 0.f; }
  __syncthreads();

  const int  g0   = tid;
  const int  g1   = tid + 256;
  const bool has2 = (g1 < G);

  for (int step = 0; step < Tt; ++step) {
    const int t = dir ? (Tt - 1 - step) : step;
    if (tid < RB * IN) {
      int r = tid / IN, k = tid - r * IN;
      x_s[r][k] = x[((b0 + r) * Tt + t) * IN + k];
    }
    __syncthreads();

    // ---- gates: acc[g][r] = bias + W_ih x + W_hh h ----
    float acc0[RB], acc1[RB];
    {
      float bb0 = bias_s[g0];
      float bb1 = has2 ? bias_s[g1] : 0.f;
#pragma unroll
      for (int r = 0; r < RB; ++r) { acc0[r] = bb0; acc1[r] = bb1; }
    }
#pragma unroll
    for (int k = 0; k < IN; ++k) {
      float xr[RB];
#pragma unroll
      for (int r = 0; r < RB; ++r) xr[r] = x_s[r][k];   // broadcast
      float w0 = wih_s[g0 * IN + k];
#pragma unroll
      for (int r = 0; r < RB; ++r) acc0[r] += w0 * xr[r];
      if (has2) {
        float w1 = wih_s[g1 * IN + k];
#pragma unroll
        for (int r = 0; r < RB; ++r) acc1[r] += w1 * xr[r];
      }
    }
    for (int kc = 0; kc < H / 4; ++kc) {
      float4 hr[RB];
#pragma unroll
      for (int r = 0; r < RB; ++r) hr[r] = h4[r][kc];   // broadcast b128
      float4 w0 = pk[kc * G + g0];                       // coalesced
#pragma unroll
      for (int r = 0; r < RB; ++r)
        acc0[r] += w0.x * hr[r].x + w0.y * hr[r].y + w0.z * hr[r].z + w0.w * hr[r].w;
      if (has2) {
        float4 w1 = pk[kc * G + g1];
#pragma unroll
        for (int r = 0; r < RB; ++r)
          acc1[r] += w1.x * hr[r].x + w1.y * hr[r].y + w1.z * hr[r].z + w1.w * hr[r].w;
      }
    }
#pragma unroll
    for (int r = 0; r < RB; ++r) gbuf[r][g0] = acc0[r];
    if (has2) {
#pragma unroll
      for (int r = 0; r < RB; ++r) gbuf[r][g1] = acc1[r];
    }
    __syncthreads();

    // ---- cell update + h0 write ----
    for (int idx = tid; idx < RB * H; idx += 256) {
      int r = idx / H, j = idx - r * H;
      float ig = sigm(gbuf[r][j]);
      float fg = sigm(gbuf[r][H + j]);
      float gg = tanh_f(gbuf[r][2 * H + j]);
      float og = sigm(gbuf[r][3 * H + j]);
      float c  = fg * c_s[r][j] + ig * gg;
      c_s[r][j] = c;
      float h = og * tanh_f(c);
      hrow[r * H + j] = h;
      h0[((size_t)(b0 + r) * Tt + t) * D1 + dir * H + j] = h;
    }
    __syncthreads();
  }
}

// ------- layer 1: fwd scan + bwd single step + FC + softmax, fused -------
__global__ __launch_bounds__(256) void lstm_l1(
    const float* __restrict__ h0,
    const float* __restrict__ bih_f, const float* __restrict__ bhh_f,
    const float4* __restrict__ pk_ih_f, const float4* __restrict__ pk_hh_f,
    const float* __restrict__ bih_b, const float* __restrict__ bhh_b,
    const float4* __restrict__ pk_ih_b,
    const float* __restrict__ fc_w, const float* __restrict__ fc_b,
    float* __restrict__ out)
{
  __shared__ float4 in4[RB][D1 / 4];
  __shared__ float4 h4[RB][H / 4];
  __shared__ float  c_s[RB][H];
  __shared__ float  gbuf[RB][G];
  __shared__ float  bias_s[G];
  __shared__ float  hb_s[RB][H];
  __shared__ float  logit_s[RB][3];

  const int tid = threadIdx.x;
  const int b0  = blockIdx.x * RB;
  float* hrow = (float*)h4;
  const float4* h0_4 = (const float4*)h0;

  for (int i = tid; i < G; i += 256)      bias_s[i] = bih_f[i] + bhh_f[i];
  for (int i = tid; i < RB * H; i += 256) { hrow[i] = 0.f; (&c_s[0][0])[i] = 0.f; }
  __syncthreads();

  const int  g0   = tid;
  const int  g1   = tid + 256;
  const bool has2 = (g1 < G);

  for (int t = 0; t < Tt; ++t) {
    for (int i = tid; i < RB * (D1 / 4); i += 256) {
      int r = i / (D1 / 4), c = i - r * (D1 / 4);
      in4[r][c] = h0_4[((size_t)(b0 + r) * Tt + t) * (D1 / 4) + c];
    }
    __syncthreads();

    float acc0[RB], acc1[RB];
    {
      float bb0 = bias_s[g0];
      float bb1 = has2 ? bias_s[g1] : 0.f;
#pragma unroll
      for (int r = 0; r < RB; ++r) { acc0[r] = bb0; acc1[r] = bb1; }
    }
    for (int kc = 0; kc < D1 / 4; ++kc) {          // input projection K=200
      float4 xr[RB];
#pragma unroll
      for (int r = 0; r < RB; ++r) xr[r] = in4[r][kc];
      float4 w0 = pk_ih_f[kc * G + g0];
#pragma unroll
      for (int r = 0; r < RB; ++r)
        acc0[r] += w0.x * xr[r].x + w0.y * xr[r].y + w0.z * xr[r].z + w0.w * xr[r].w;
      if (has2) {
        float4 w1 = pk_ih_f[kc * G + g1];
#pragma unroll
        for (int r = 0; r < RB; ++r)
          acc1[r] += w1.x * xr[r].x + w1.y * xr[r].y + w1.z * xr[r].z + w1.w * xr[r].w;
      }
    }
    for (int kc = 0; kc < H / 4; ++kc) {           // recurrent K=100
      float4 hr[RB];
#pragma unroll
      for (int r = 0; r < RB; ++r) hr[r] = h4[r][kc];
      float4 w0 = pk_hh_f[kc * G + g0];
#pragma unroll
      for (int r = 0; r < RB; ++r)
        acc0[r] += w0.x * hr[r].x + w0.y * hr[r].y + w0.z * hr[r].z + w0.w * hr[r].w;
      if (has2) {
        float4 w1 = pk_hh_f[kc * G + g1];
#pragma unroll
        for (int r = 0; r < RB; ++r)
          acc1[r] += w1.x * hr[r].x + w1.y * hr[r].y + w1.z * hr[r].z + w1.w * hr[r].w;
      }
    }
#pragma unroll
    for (int r = 0; r < RB; ++r) gbuf[r][g0] = acc0[r];
    if (has2) {
#pragma unroll
      for (int r = 0; r < RB; ++r) gbuf[r][g1] = acc1[r];
    }
    __syncthreads();

    for (int idx = tid; idx < RB * H; idx += 256) {
      int r = idx / H, j = idx - r * H;
      float ig = sigm(gbuf[r][j]);
      float fg = sigm(gbuf[r][H + j]);
      float gg = tanh_f(gbuf[r][2 * H + j]);
      float og = sigm(gbuf[r][3 * H + j]);
      float c  = fg * c_s[r][j] + ig * gg;
      c_s[r][j] = c;
      hrow[r * H + j] = og * tanh_f(c);   // only last t is consumed
    }
    __syncthreads();
  }

  // ---- layer-1 backward, single step at t=T-1 (h=c=0); in4 still holds it ----
  {
    float acc0[RB], acc1[RB];
    float bb0 = bih_b[g0] + bhh_b[g0];
    float bb1 = has2 ? (bih_b[g1] + bhh_b[g1]) : 0.f;
#pragma unroll
    for (int r = 0; r < RB; ++r) { acc0[r] = bb0; acc1[r] = bb1; }
    for (int kc = 0; kc < D1 / 4; ++kc) {
      float4 xr[RB];
#pragma unroll
      for (int r = 0; r < RB; ++r) xr[r] = in4[r][kc];
      float4 w0 = pk_ih_b[kc * G + g0];
#pragma unroll
      for (int r = 0; r < RB; ++r)
        acc0[r] += w0.x * xr[r].x + w0.y * xr[r].y + w0.z * xr[r].z + w0.w * xr[r].w;
      if (has2) {
        float4 w1 = pk_ih_b[kc * G + g1];
#pragma unroll
        for (int r = 0; r < RB; ++r)
          acc1[r] += w1.x * xr[r].x + w1.y * xr[r].y + w1.z * xr[r].z + w1.w * xr[r].w;
      }
    }
#pragma unroll
    for (int r = 0; r < RB; ++r) gbuf[r][g0] = acc0[r];
    if (has2) {
#pragma unroll
      for (int r = 0; r < RB; ++r) gbuf[r][g1] = acc1[r];
    }
  }
  __syncthreads();
  for (int idx = tid; idx < RB * H; idx += 256) {
    int r = idx / H, j = idx - r * H;
    float ig = sigm(gbuf[r][j]);
    float gg = tanh_f(gbuf[r][2 * H + j]);
    float og = sigm(gbuf[r][3 * H + j]);
    float c  = ig * gg;                   // c_prev = 0
    hb_s[r][j] = og * tanh_f(c);
  }
  __syncthreads();

  // ---- FC (3x200) + softmax ----
  for (int idx = tid; idx < RB * 3; idx += 256) {
    int r = idx / 3, cls = idx - r * 3;
    float a = fc_b[cls];
    for (int k = 0; k < H; ++k) a += fc_w[cls * D1 + k]     * hrow[r * H + k];
    for (int k = 0; k < H; ++k) a += fc_w[cls * D1 + H + k] * hb_s[r][k];
    logit_s[r][cls] = a;
  }
  __syncthreads();
  if (tid < RB) {
    int r = tid;
    float l0v = logit_s[r][0], l1v = logit_s[r][1], l2v = logit_s[r][2];
    float m  = fmaxf(l0v, fmaxf(l1v, l2v));
    float e0 = __expf(l0v - m), e1 = __expf(l1v - m), e2 = __expf(l2v - m);
    float inv = 1.f / (e0 + e1 + e2);
    out[(b0 + r) * 3 + 0] = e0 * inv;
    out[(b0 + r) * 3 + 1] = e1 * inv;
    out[(b0 + r) * 3 + 2] = e2 * inv;
  }
}

extern "C" void kernel_launch(void* const* d_in, const int* in_sizes, int n_in,
                              void* d_out, int out_size, void* d_ws, size_t ws_size,
                              hipStream_t stream) {
  const float* x        = (const float*)d_in[0];
  const float* w_ih_l0f = (const float*)d_in[1];
  const float* w_hh_l0f = (const float*)d_in[2];
  const float* b_ih_l0f = (const float*)d_in[3];
  const float* b_hh_l0f = (const float*)d_in[4];
  const float* w_ih_l0b = (const float*)d_in[5];
  const float* w_hh_l0b = (const float*)d_in[6];
  const float* b_ih_l0b = (const float*)d_in[7];
  const float* b_hh_l0b = (const float*)d_in[8];
  const float* w_ih_l1f = (const float*)d_in[9];
  const float* w_hh_l1f = (const float*)d_in[10];
  const float* b_ih_l1f = (const float*)d_in[11];
  const float* b_hh_l1f = (const float*)d_in[12];
  const float* w_ih_l1b = (const float*)d_in[13];
  // d_in[14] = w_hh_l1b: unused (reverse dir at t=T-1 has h=0)
  const float* b_ih_l1b = (const float*)d_in[15];
  const float* b_hh_l1b = (const float*)d_in[16];
  const float* fc_w     = (const float*)d_in[17];
  const float* fc_b     = (const float*)d_in[18];

  float* ws      = (float*)d_ws;
  float* h0      = ws;                         // 1024*128*200 = 26,214,400 floats
  float* pk_hh0f = ws + (size_t)Bsz * Tt * D1; // 40,000
  float* pk_hh0b = pk_hh0f + G * H;            // 40,000
  float* pk_ih1f = pk_hh0b + G * H;            // 80,000
  float* pk_hh1f = pk_ih1f + G * D1;           // 40,000
  float* pk_ih1b = pk_hh1f + G * H;            // 80,000

  pack_w<<<(G * H  + 255) / 256, 256, 0, stream>>>(w_hh_l0f, pk_hh0f, G, H);
  pack_w<<<(G * H  + 255) / 256, 256, 0, stream>>>(w_hh_l0b, pk_hh0b, G, H);
  pack_w<<<(G * D1 + 255) / 256, 256, 0, stream>>>(w_ih_l1f, pk_ih1f, G, D1);
  pack_w<<<(G * H  + 255) / 256, 256, 0, stream>>>(w_hh_l1f, pk_hh1f, G, H);
  pack_w<<<(G * D1 + 255) / 256, 256, 0, stream>>>(w_ih_l1b, pk_ih1b, G, D1);

  lstm_l0<<<dim3(Bsz / RB, 2), 256, 0, stream>>>(
      x, w_ih_l0f, b_ih_l0f, b_hh_l0f, w_ih_l0b, b_ih_l0b, b_hh_l0b,
      (const float4*)pk_hh0f, (const float4*)pk_hh0b, h0);

  lstm_l1<<<Bsz / RB, 256, 0, stream>>>(
      h0, b_ih_l1f, b_hh_l1f, (const float4*)pk_ih1f, (const float4*)pk_hh1f,
      b_ih_l1b, b_hh_l1b, (const float4*)pk_ih1b, fc_w, fc_b, (float*)d_out);
}

// Round 2
// 1031.278 us; speedup vs baseline: 4.8223x; 4.8223x over previous
//
#include <hip/hip_runtime.h>
#include <hip/hip_fp16.h>

// LSTM_48850958024796 — MFMA bf16 rewrite.
// Structure:
//   pack_aug  : fp32 weights -> bf16 packed [Kgroup][448][8] (augmented cols:
//               W_hh | W_ih | bias-as-k-column), MFMA-B-fragment-ready
//   lstm_l0   : 128 blocks (64 batch-tiles x 2 dirs). Per step one 16x448x128
//               MFMA GEMM with A=[h|x_t|1] (bf16, LDS), B register-resident.
//               fp32 cell state + nonlinearities. Writes h0 bf16 [B][T][200].
//   gemm_xg   : xg1f[B*T][400] = h0 @ W_ih_l1f^T + bias  (bf16 MFMA, fp16 out)
//   lstm_l1   : 64 blocks. Scan: gates = xg1f[t] + h @ W_hh1f^T (MFMA, B in
//               regs). Epilogue: l1-backward single step (t=T-1, h=c=0) via
//               MFMA with streamed W_ih_l1b, then FC(3x200)+softmax.
// MFMA 16x16x32 bf16 layouts (m89/m91-verified): A[m=lane&15][k=(lane>>4)*8+j],
// B[n=lane&15][k=(lane>>4)*8+j], D[row=(lane>>4)*4+reg][col=lane&15].

typedef __attribute__((ext_vector_type(8))) short bf16x8;
typedef __attribute__((ext_vector_type(4))) float f32x4;

constexpr int Bsz = 1024, Tt = 128, IN_ = 5, H = 100, G = 400, D1 = 200;
constexpr int NP = 448;   // padded gate dim (28 MFMA N-tiles)
constexpr int NT = 25;    // real N-tiles (400/16)
constexpr int GP = 452;   // gbuf padded row stride (floats)

__device__ __forceinline__ float sigm(float x)   { return 1.f / (1.f + __expf(-x)); }
__device__ __forceinline__ float tanhf_(float x) { return 1.f - 2.f / (__expf(2.f * x) + 1.f); }
__device__ __forceinline__ unsigned short f2bf(float f) {
  unsigned u = __float_as_uint(f);
  u += 0x7fff + ((u >> 16) & 1);
  return (unsigned short)(u >> 16);
}

// dst[(g*448+n)*8+j] = bf16 of augmented W: k=g*8+j; k<KA -> wA[n][k];
// KA<=k<KA+KB -> wB[n][k-KA]; k==bias_k -> b1[n]+b2[n]; else 0. n>=400 -> 0.
__global__ void pack_aug(const float* __restrict__ wA, int KA,
                         const float* __restrict__ wB, int KB,
                         const float* __restrict__ b1, const float* __restrict__ b2,
                         int bias_k, unsigned short* __restrict__ dst, int Kg) {
  int idx = blockIdx.x * 256 + threadIdx.x;
  int total = Kg * NP * 8;
  if (idx >= total) return;
  int j = idx & 7, rest = idx >> 3;
  int n = rest % NP, g = rest / NP;
  int k = g * 8 + j;
  float v = 0.f;
  if (n < G) {
    if (k < KA) v = wA[n * KA + k];
    else if (k < KA + KB) v = wB[n * KB + (k - KA)];
    else if (k == bias_k) v = b1[n] + b2[n];
  }
  dst[idx] = f2bf(v);
}

// ---------------- layer 0 scan (grid = 64 x 2 dirs) ----------------
__global__ __launch_bounds__(256, 1) void lstm_l0(
    const float* __restrict__ x,
    const unsigned short* __restrict__ pk_f, const unsigned short* __restrict__ pk_b,
    unsigned short* __restrict__ h0) {
  __shared__ __align__(16) short A_s[16][16][8];  // [kgroup][m][j], K=128
  __shared__ float gbuf[16][GP];
  __shared__ float c_s[16][H];

  const int tid = threadIdx.x;
  const int lane = tid & 63, w = tid >> 6;
  const int q = lane >> 4, l16 = lane & 15;
  const int b0 = blockIdx.x * 16;
  const int dir = blockIdx.y;
  const unsigned short* pk = dir ? pk_b : pk_f;

  for (int i = tid; i < 16 * 16 * 8; i += 256) ((short*)A_s)[i] = 0;
  for (int i = tid; i < 16 * H; i += 256) ((float*)c_s)[i] = 0.f;
  __syncthreads();
  {  // x(t_first) and the bias-one column (k=105)
    int t0 = dir ? (Tt - 1) : 0;
    if (tid < 80) {
      int m = tid / 5, e = tid - m * 5, k = 100 + e;
      A_s[k >> 3][m][k & 7] = (short)f2bf(x[((b0 + m) * Tt + t0) * IN_ + e]);
    }
    if (tid < 16) A_s[105 >> 3][tid][105 & 7] = (short)f2bf(1.f);
  }

  // register-resident B fragments: 7 N-tiles per wave x 4 k-steps
  bf16x8 bfrag[7][4];
#pragma unroll
  for (int i = 0; i < 7; ++i) {
    int nt = w + 4 * i;  // 0..27, all valid in the 448-wide pack
#pragma unroll
    for (int kt = 0; kt < 4; ++kt)
      bfrag[i][kt] = *(const bf16x8*)(pk + ((size_t)((kt * 4 + q) * NP) + nt * 16 + l16) * 8);
  }
  __syncthreads();

  for (int step = 0; step < Tt; ++step) {
    const int t = dir ? (Tt - 1 - step) : step;
    // phase 1: gates = [h|x|1] @ Waug^T
    bf16x8 afrag[4];
#pragma unroll
    for (int kt = 0; kt < 4; ++kt) afrag[kt] = *(const bf16x8*)A_s[kt * 4 + q][l16];
    f32x4 acc[7];
#pragma unroll
    for (int i = 0; i < 7; ++i) {
      acc[i] = (f32x4){0.f, 0.f, 0.f, 0.f};
#pragma unroll
      for (int kt = 0; kt < 4; ++kt)
        acc[i] = __builtin_amdgcn_mfma_f32_16x16x32_bf16(afrag[kt], bfrag[i][kt], acc[i], 0, 0, 0);
    }
#pragma unroll
    for (int i = 0; i < 7; ++i) {
      int nt = w + 4 * i;
      if (nt < NT) {
#pragma unroll
        for (int r = 0; r < 4; ++r) gbuf[q * 4 + r][nt * 16 + l16] = acc[i][r];
      }
    }
    __syncthreads();
    // phase 2: cell update; write h (bf16) into A_s + h0 global
    for (int idx = tid; idx < 16 * H; idx += 256) {
      int m = idx / H, j = idx - m * H;
      float ig = sigm(gbuf[m][j]);
      float fg = sigm(gbuf[m][H + j]);
      float gg = tanhf_(gbuf[m][2 * H + j]);
      float og = sigm(gbuf[m][3 * H + j]);
      float c = fg * c_s[m][j] + ig * gg;
      c_s[m][j] = c;
      float h = og * tanhf_(c);
      unsigned short hb = f2bf(h);
      A_s[j >> 3][m][j & 7] = (short)hb;
      h0[((size_t)(b0 + m) * Tt + t) * D1 + dir * H + j] = hb;
    }
    if (step < Tt - 1 && tid < 80) {  // stage x for next step
      int tn = dir ? (Tt - 2 - step) : (step + 1);
      int m = tid / 5, e = tid - m * 5, k = 100 + e;
      A_s[k >> 3][m][k & 7] = (short)f2bf(x[((b0 + m) * Tt + tn) * IN_ + e]);
    }
    __syncthreads();
  }
}

// ---------------- xg1 = h0 @ W_ih_l1f^T + bias (fp16 out) ----------------
__global__ __launch_bounds__(256, 2) void gemm_xg(
    const unsigned short* __restrict__ h0, const unsigned short* __restrict__ pkw,
    __half* __restrict__ xg) {
  __shared__ __align__(16) short A_s[28][64][8];  // K=224 aug (k=200 is bias-one)
  __shared__ __align__(16) short B_s[28][64][8];
  const int tid = threadIdx.x;
  const int lane = tid & 63, w = tid >> 6;
  const int q = lane >> 4, l16 = lane & 15;
  const int r0 = blockIdx.x * 64;

  // stage A rows (64 x 200 bf16) + zero/one the aug tail (groups 25..27)
  for (int c = tid; c < 64 * 25; c += 256) {
    int m = c / 25, g = c - m * 25;
    *(uint4*)A_s[g][m] = *(const uint4*)(h0 + (size_t)(r0 + m) * D1 + g * 8);
  }
  for (int i = tid; i < 3 * 64 * 8; i += 256) {
    int j = i & 7, gl = i >> 9;  // gl: 0..2 -> groups 25..27
    ((short*)&A_s[25][0][0])[i] = (short)((gl == 0 && j == 0) ? f2bf(1.f) : 0);
  }
  __syncthreads();

  for (int nb = 0; nb < 7; ++nb) {
    for (int c = tid; c < 28 * 64; c += 256) {
      int g = c >> 6, col = c & 63;
      *(uint4*)B_s[g][col] = *(const uint4*)(pkw + ((size_t)g * NP + nb * 64 + col) * 8);
    }
    __syncthreads();
    f32x4 acc[4];
#pragma unroll
    for (int nt = 0; nt < 4; ++nt) acc[nt] = (f32x4){0.f, 0.f, 0.f, 0.f};
#pragma unroll
    for (int kt = 0; kt < 7; ++kt) {
      bf16x8 af = *(const bf16x8*)A_s[kt * 4 + q][w * 16 + l16];
#pragma unroll
      for (int nt = 0; nt < 4; ++nt) {
        bf16x8 bf = *(const bf16x8*)B_s[kt * 4 + q][nt * 16 + l16];
        acc[nt] = __builtin_amdgcn_mfma_f32_16x16x32_bf16(af, bf, acc[nt], 0, 0, 0);
      }
    }
#pragma unroll
    for (int nt = 0; nt < 4; ++nt) {
      int col = nb * 64 + nt * 16 + l16;
      if (col < G) {
#pragma unroll
        for (int r = 0; r < 4; ++r) {
          int row = r0 + w * 16 + q * 4 + r;
          xg[(size_t)row * G + col] = __float2half(acc[nt][r]);
        }
      }
    }
    __syncthreads();
  }
}

// -------- layer 1: fwd scan + bwd single step + FC + softmax --------
__global__ __launch_bounds__(256, 1) void lstm_l1(
    const unsigned short* __restrict__ h0,
    const unsigned short* __restrict__ pk_hh, const unsigned short* __restrict__ pk_ihb,
    const __half* __restrict__ xg,
    const float* __restrict__ fc_w, const float* __restrict__ fc_b,
    float* __restrict__ out) {
  __shared__ __align__(16) short A_s[28][16][8];  // scan uses groups 0..15; l1b 0..27
  __shared__ float gbuf[16][GP];
  __shared__ float c_s[16][H];
  __shared__ float hf_s[16][H];
  __shared__ float hb_s[16][H];
  __shared__ float fcw_s[3 * D1];
  __shared__ float fcb_s[3];
  __shared__ float logit_s[16][3];

  const int tid = threadIdx.x;
  const int lane = tid & 63, w = tid >> 6;
  const int q = lane >> 4, l16 = lane & 15;
  const int b0 = blockIdx.x * 16;

  for (int i = tid; i < 28 * 16 * 8; i += 256) ((short*)A_s)[i] = 0;
  for (int i = tid; i < 16 * H; i += 256) ((float*)c_s)[i] = 0.f;
  for (int i = tid; i < 3 * D1; i += 256) fcw_s[i] = fc_w[i];
  if (tid < 3) fcb_s[tid] = fc_b[tid];

  bf16x8 bfrag[7][4];
#pragma unroll
  for (int i = 0; i < 7; ++i) {
    int nt = w + 4 * i;
#pragma unroll
    for (int kt = 0; kt < 4; ++kt)
      bfrag[i][kt] = *(const bf16x8*)(pk_hh + ((size_t)((kt * 4 + q) * NP) + nt * 16 + l16) * 8);
  }
  __syncthreads();

  for (int t = 0; t < Tt; ++t) {
    // prefetch xg slice first (HBM latency hides behind the MFMAs)
    float xgv[7][4];
#pragma unroll
    for (int i = 0; i < 7; ++i) {
      int nt = w + 4 * i;
      if (nt < NT) {
#pragma unroll
        for (int r = 0; r < 4; ++r)
          xgv[i][r] = __half2float(xg[((size_t)(b0 + q * 4 + r) * Tt + t) * G + nt * 16 + l16]);
      }
    }
    bf16x8 afrag[4];
#pragma unroll
    for (int kt = 0; kt < 4; ++kt) afrag[kt] = *(const bf16x8*)A_s[kt * 4 + q][l16];
    f32x4 acc[7];
#pragma unroll
    for (int i = 0; i < 7; ++i) {
      acc[i] = (f32x4){0.f, 0.f, 0.f, 0.f};
#pragma unroll
      for (int kt = 0; kt < 4; ++kt)
        acc[i] = __builtin_amdgcn_mfma_f32_16x16x32_bf16(afrag[kt], bfrag[i][kt], acc[i], 0, 0, 0);
    }
#pragma unroll
    for (int i = 0; i < 7; ++i) {
      int nt = w + 4 * i;
      if (nt < NT) {
#pragma unroll
        for (int r = 0; r < 4; ++r) gbuf[q * 4 + r][nt * 16 + l16] = acc[i][r] + xgv[i][r];
      }
    }
    __syncthreads();
    for (int idx = tid; idx < 16 * H; idx += 256) {
      int m = idx / H, j = idx - m * H;
      float ig = sigm(gbuf[m][j]);
      float fg = sigm(gbuf[m][H + j]);
      float gg = tanhf_(gbuf[m][2 * H + j]);
      float og = sigm(gbuf[m][3 * H + j]);
      float c = fg * c_s[m][j] + ig * gg;
      c_s[m][j] = c;
      float h = og * tanhf_(c);
      A_s[j >> 3][m][j & 7] = (short)f2bf(h);
      if (t == Tt - 1) hf_s[m][j] = h;
    }
    __syncthreads();
  }

  // ---- layer-1 backward, single step at t=T-1 (h=c=0) ----
  // A := [h0[:,T-1,0:200] | 1] (both halves from layer-0 output)
  for (int idx = tid; idx < 16 * D1; idx += 256) {
    int m = idx / D1, k = idx - m * D1;
    A_s[k >> 3][m][k & 7] = (short)h0[((size_t)(b0 + m) * Tt + (Tt - 1)) * D1 + k];
  }
  if (tid < 16) A_s[200 >> 3][tid][200 & 7] = (short)f2bf(1.f);
  __syncthreads();
  {
    f32x4 acc[7];
#pragma unroll
    for (int i = 0; i < 7; ++i) acc[i] = (f32x4){0.f, 0.f, 0.f, 0.f};
#pragma unroll
    for (int kt = 0; kt < 7; ++kt) {
      bf16x8 af = *(const bf16x8*)A_s[kt * 4 + q][l16];
#pragma unroll
      for (int i = 0; i < 7; ++i) {
        int nt = w + 4 * i;
        bf16x8 bf = *(const bf16x8*)(pk_ihb + ((size_t)((kt * 4 + q) * NP) + nt * 16 + l16) * 8);
        acc[i] = __builtin_amdgcn_mfma_f32_16x16x32_bf16(af, bf, acc[i], 0, 0, 0);
      }
    }
#pragma unroll
    for (int i = 0; i < 7; ++i) {
      int nt = w + 4 * i;
      if (nt < NT) {
#pragma unroll
        for (int r = 0; r < 4; ++r) gbuf[q * 4 + r][nt * 16 + l16] = acc[i][r];
      }
    }
  }
  __syncthreads();
  for (int idx = tid; idx < 16 * H; idx += 256) {
    int m = idx / H, j = idx - m * H;
    float ig = sigm(gbuf[m][j]);
    float gg = tanhf_(gbuf[m][2 * H + j]);
    float og = sigm(gbuf[m][3 * H + j]);
    float c = ig * gg;  // c_prev = 0
    hb_s[m][j] = og * tanhf_(c);
  }
  __syncthreads();

  // ---- FC + softmax ----
  if (tid < 48) {
    int m = tid / 3, cls = tid - m * 3;
    float s = fcb_s[cls];
    for (int j = 0; j < H; ++j) s += fcw_s[cls * D1 + j] * hf_s[m][j];
    for (int j = 0; j < H; ++j) s += fcw_s[cls * D1 + H + j] * hb_s[m][j];
    logit_s[m][cls] = s;
  }
  __syncthreads();
  if (tid < 16) {
    float a = logit_s[tid][0], b = logit_s[tid][1], c = logit_s[tid][2];
    float mx = fmaxf(a, fmaxf(b, c));
    float e0 = __expf(a - mx), e1 = __expf(b - mx), e2 = __expf(c - mx);
    float inv = 1.f / (e0 + e1 + e2);
    out[(b0 + tid) * 3 + 0] = e0 * inv;
    out[(b0 + tid) * 3 + 1] = e1 * inv;
    out[(b0 + tid) * 3 + 2] = e2 * inv;
  }
}

extern "C" void kernel_launch(void* const* d_in, const int* in_sizes, int n_in,
                              void* d_out, int out_size, void* d_ws, size_t ws_size,
                              hipStream_t stream) {
  const float* x        = (const float*)d_in[0];
  const float* w_ih_l0f = (const float*)d_in[1];
  const float* w_hh_l0f = (const float*)d_in[2];
  const float* b_ih_l0f = (const float*)d_in[3];
  const float* b_hh_l0f = (const float*)d_in[4];
  const float* w_ih_l0b = (const float*)d_in[5];
  const float* w_hh_l0b = (const float*)d_in[6];
  const float* b_ih_l0b = (const float*)d_in[7];
  const float* b_hh_l0b = (const float*)d_in[8];
  const float* w_ih_l1f = (const float*)d_in[9];
  const float* w_hh_l1f = (const float*)d_in[10];
  const float* b_ih_l1f = (const float*)d_in[11];
  const float* b_hh_l1f = (const float*)d_in[12];
  const float* w_ih_l1b = (const float*)d_in[13];
  // d_in[14] = w_hh_l1b unused (reverse dir at t=T-1 has h=0)
  const float* b_ih_l1b = (const float*)d_in[15];
  const float* b_hh_l1b = (const float*)d_in[16];
  const float* fc_w     = (const float*)d_in[17];
  const float* fc_b     = (const float*)d_in[18];

  // ws layout (bytes): h0 bf16 52.4MB | xg fp16 104.9MB | 5 packed weights
  unsigned short* h0 = (unsigned short*)d_ws;                      // 26,214,400 el
  __half* xg = (__half*)(h0 + (size_t)Bsz * Tt * D1);              // 52,428,800 el
  unsigned short* pk0f   = (unsigned short*)(xg + (size_t)Bsz * Tt * G);
  unsigned short* pk0b   = pk0f + 16 * NP * 8;
  unsigned short* pkhh1f = pk0b + 16 * NP * 8;
  unsigned short* pkih1f = pkhh1f + 16 * NP * 8;
  unsigned short* pkih1b = pkih1f + 28 * NP * 8;

  const int P16 = (16 * NP * 8 + 255) / 256, P28 = (28 * NP * 8 + 255) / 256;
  pack_aug<<<P16, 256, 0, stream>>>(w_hh_l0f, H, w_ih_l0f, IN_, b_ih_l0f, b_hh_l0f, 105, pk0f, 16);
  pack_aug<<<P16, 256, 0, stream>>>(w_hh_l0b, H, w_ih_l0b, IN_, b_ih_l0b, b_hh_l0b, 105, pk0b, 16);
  pack_aug<<<P16, 256, 0, stream>>>(w_hh_l1f, H, w_hh_l1f, 0, b_ih_l1f, b_hh_l1f, -1, pkhh1f, 16);
  pack_aug<<<P28, 256, 0, stream>>>(w_ih_l1f, D1, w_ih_l1f, 0, b_ih_l1f, b_hh_l1f, 200, pkih1f, 28);
  pack_aug<<<P28, 256, 0, stream>>>(w_ih_l1b, D1, w_ih_l1b, 0, b_ih_l1b, b_hh_l1b, 200, pkih1b, 28);

  lstm_l0<<<dim3(Bsz / 16, 2), 256, 0, stream>>>(x, pk0f, pk0b, h0);
  gemm_xg<<<(Bsz * Tt) / 64, 256, 0, stream>>>(h0, pkih1f, xg);
  lstm_l1<<<Bsz / 16, 256, 0, stream>>>(h0, pkhh1f, pkih1b, xg, fc_w, fc_b, (float*)d_out);
}

// Round 3
// 718.034 us; speedup vs baseline: 6.9261x; 1.4363x over previous
//
#include <hip/hip_runtime.h>
#include <hip/hip_fp16.h>

// LSTM_48850958024796 — R3: weight-stationary MFMA scan, register cell state.
// Key trick: gates^T = W_aug(A-operand) @ [h|x|1]^T(B-operand) with columns
// packed gate-interleaved (col' = 4j+gate). MFMA D-layout then yields all 4
// gates of one (batch m, hidden j) in the 4 acc regs of ONE lane:
//   lane(q,l16), tile mt: (m=l16, j=mt*4+q), gates i,f,g,o = acc[0..3].
// Cell update is pure per-lane register math; c[] lives in VGPRs across all
// 128 steps; A_s (h in MFMA-fragment layout) double-buffered -> 1 barrier/step.

typedef __attribute__((ext_vector_type(8))) short bf16x8;
typedef __attribute__((ext_vector_type(4))) float f32x4;

constexpr int Bsz = 1024, Tt = 128, IN_ = 5, H = 100, G = 400, D1 = 200;
constexpr int NP = 448;   // padded gate dim (28 MFMA tiles of 16)
constexpr int NT = 25;    // real tiles (400/16)

__device__ __forceinline__ float sigm(float x)   { return 1.f / (1.f + __expf(-x)); }
__device__ __forceinline__ float tanhf_(float x) { return 1.f - 2.f / (__expf(2.f * x) + 1.f); }
__device__ __forceinline__ unsigned short f2bf(float f) {
  unsigned u = __float_as_uint(f);
  u += 0x7fff + ((u >> 16) & 1);
  return (unsigned short)(u >> 16);
}

// packed col n' (0..447): j=n'>>2, gate=n'&3, src row = gate*100+j; j>=100 -> 0
// dst[(g*NP+n')*8+jj], k=g*8+jj: k<KA -> wA[src][k]; KA<=k<KA+KB -> wB[src][k-KA];
// k==bias_k -> b1[src]+b2[src]; else 0.
__global__ void pack_aug(const float* __restrict__ wA, int KA,
                         const float* __restrict__ wB, int KB,
                         const float* __restrict__ b1, const float* __restrict__ b2,
                         int bias_k, unsigned short* __restrict__ dst, int Kg) {
  int idx = blockIdx.x * 256 + threadIdx.x;
  int total = Kg * NP * 8;
  if (idx >= total) return;
  int jj = idx & 7, rest = idx >> 3;
  int np_ = rest % NP, g = rest / NP;
  int j = np_ >> 2, gate = np_ & 3;
  int k = g * 8 + jj;
  float v = 0.f;
  if (j < H) {
    int n = gate * H + j;
    if (k < KA) v = wA[n * KA + k];
    else if (k < KA + KB) v = wB[n * KB + (k - KA)];
    else if (k == bias_k) v = b1[n] + b2[n];
  }
  dst[idx] = f2bf(v);
}

// ---------------- layer 0 scan (grid = 64 x 2 dirs) ----------------
__global__ __launch_bounds__(256, 1) void lstm_l0(
    const float* __restrict__ x,
    const unsigned short* __restrict__ pk_f, const unsigned short* __restrict__ pk_b,
    unsigned short* __restrict__ h0) {
  __shared__ __align__(16) short A_s[2][16][16][8];  // [buf][kgroup][m][jj]

  const int tid = threadIdx.x;
  const int lane = tid & 63, w = tid >> 6;
  const int q = lane >> 4, l16 = lane & 15;
  const int b0 = blockIdx.x * 16;
  const int dir = blockIdx.y;
  const unsigned short* pk = dir ? pk_b : pk_f;

  for (int i = tid; i < 2 * 16 * 16 * 8; i += 256) ((short*)A_s)[i] = 0;
  __syncthreads();
  if (tid < 16) {  // bias-one column k=105 (kg13, jj1), both buffers
    A_s[0][13][tid][1] = (short)f2bf(1.f);
    A_s[1][13][tid][1] = (short)f2bf(1.f);
  }
  {  // x(t_first) into buf 0 (k=100..104)
    int t0 = dir ? (Tt - 1) : 0;
    if (tid < 80) {
      int m = tid / 5, e = tid - m * 5, k = 100 + e;
      A_s[0][k >> 3][m][k & 7] = (short)f2bf(x[((b0 + m) * Tt + t0) * IN_ + e]);
    }
  }

  bf16x8 wfrag[7][4];
#pragma unroll
  for (int i = 0; i < 7; ++i)
#pragma unroll
    for (int kt = 0; kt < 4; ++kt)
      wfrag[i][kt] = *(const bf16x8*)(pk + ((size_t)(kt * 4 + q) * NP + (w + 4 * i) * 16 + l16) * 8);

  float c[7];
#pragma unroll
  for (int i = 0; i < 7; ++i) c[i] = 0.f;
  const size_t hbase = (size_t)(b0 + l16) * Tt * D1 + dir * H;
  __syncthreads();

  int p = 0;
  for (int step = 0; step < Tt; ++step) {
    const int t = dir ? (Tt - 1 - step) : step;
    // prefetch next x into regs (off critical path)
    float xn = 0.f; int xm = 0, xk = 0;
    const bool do_x = (tid < 80) && (step < Tt - 1);
    if (do_x) {
      int tn = dir ? (t - 1) : (t + 1);
      xm = tid / 5; int e = tid - xm * 5; xk = 100 + e;
      xn = x[((b0 + xm) * Tt + tn) * IN_ + e];
    }
    bf16x8 hfrag[4];
#pragma unroll
    for (int kt = 0; kt < 4; ++kt) hfrag[kt] = *(const bf16x8*)A_s[p][kt * 4 + q][l16];
    f32x4 acc[7];
#pragma unroll
    for (int i = 0; i < 7; ++i) {
      acc[i] = (f32x4){0.f, 0.f, 0.f, 0.f};
#pragma unroll
      for (int kt = 0; kt < 4; ++kt)
        acc[i] = __builtin_amdgcn_mfma_f32_16x16x32_bf16(wfrag[i][kt], hfrag[kt], acc[i], 0, 0, 0);
    }
#pragma unroll
    for (int i = 0; i < 7; ++i) {
      const int mt = w + 4 * i;
      if (mt < NT) {
        const int j = mt * 4 + q;
        float cc = sigm(acc[i][1]) * c[i] + sigm(acc[i][0]) * tanhf_(acc[i][2]);
        c[i] = cc;
        float h = sigm(acc[i][3]) * tanhf_(cc);
        unsigned short hb = f2bf(h);
        A_s[1 - p][j >> 3][l16][j & 7] = (short)hb;
        h0[hbase + (size_t)t * D1 + j] = hb;
      }
    }
    if (do_x) A_s[1 - p][xk >> 3][xm][xk & 7] = (short)f2bf(xn);
    __syncthreads();
    p ^= 1;
  }
}

// ---------------- xg1 = h0 @ W_ih_l1f^T + bias (fp16 out, interleaved cols) --
__global__ __launch_bounds__(256, 2) void gemm_xg(
    const unsigned short* __restrict__ h0, const unsigned short* __restrict__ pkw,
    __half* __restrict__ xg) {
  __shared__ __align__(16) short A_s[28][64][8];  // K=224 aug (k=200 bias-one)
  __shared__ __align__(16) short B_s[28][64][8];
  const int tid = threadIdx.x;
  const int lane = tid & 63, w = tid >> 6;
  const int q = lane >> 4, l16 = lane & 15;
  const int r0 = blockIdx.x * 64;

  for (int c = tid; c < 64 * 25; c += 256) {
    int m = c / 25, g = c - m * 25;
    *(uint4*)A_s[g][m] = *(const uint4*)(h0 + (size_t)(r0 + m) * D1 + g * 8);
  }
  for (int i = tid; i < 3 * 64 * 8; i += 256) {
    int j = i & 7, gl = i >> 9;
    ((short*)&A_s[25][0][0])[i] = (short)((gl == 0 && j == 0) ? f2bf(1.f) : 0);
  }
  __syncthreads();

  for (int nb = 0; nb < 7; ++nb) {
    for (int c = tid; c < 28 * 64; c += 256) {
      int g = c >> 6, col = c & 63;
      *(uint4*)B_s[g][col] = *(const uint4*)(pkw + ((size_t)g * NP + nb * 64 + col) * 8);
    }
    __syncthreads();
    f32x4 acc[4];
#pragma unroll
    for (int nt = 0; nt < 4; ++nt) acc[nt] = (f32x4){0.f, 0.f, 0.f, 0.f};
#pragma unroll
    for (int kt = 0; kt < 7; ++kt) {
      bf16x8 af = *(const bf16x8*)A_s[kt * 4 + q][w * 16 + l16];
#pragma unroll
      for (int nt = 0; nt < 4; ++nt) {
        bf16x8 bf = *(const bf16x8*)B_s[kt * 4 + q][nt * 16 + l16];
        acc[nt] = __builtin_amdgcn_mfma_f32_16x16x32_bf16(af, bf, acc[nt], 0, 0, 0);
      }
    }
#pragma unroll
    for (int nt = 0; nt < 4; ++nt) {
      int col = nb * 64 + nt * 16 + l16;
      if (col < G) {
#pragma unroll
        for (int r = 0; r < 4; ++r) {
          int row = r0 + w * 16 + q * 4 + r;
          xg[(size_t)row * G + col] = __float2half(acc[nt][r]);
        }
      }
    }
    __syncthreads();
  }
}

// -------- layer 1: fwd scan + bwd single step + FC + softmax --------
__global__ __launch_bounds__(256, 1) void lstm_l1(
    const unsigned short* __restrict__ h0,
    const unsigned short* __restrict__ pk_hh, const unsigned short* __restrict__ pk_ihb,
    const __half* __restrict__ xg,
    const float* __restrict__ fc_w, const float* __restrict__ fc_b,
    float* __restrict__ out) {
  __shared__ __align__(16) short A_s[2][16][16][8];
  __shared__ __align__(16) short A2_s[28][16][8];   // l1b: [h0(:,127,:)|1] K=224
  __shared__ float hf_s[16][H];
  __shared__ float hb_s[16][H];
  __shared__ float fcw_s[3 * D1];
  __shared__ float fcb_s[3];
  __shared__ float logit_s[16][3];

  const int tid = threadIdx.x;
  const int lane = tid & 63, w = tid >> 6;
  const int q = lane >> 4, l16 = lane & 15;
  const int b0 = blockIdx.x * 16;

  for (int i = tid; i < 2 * 16 * 16 * 8; i += 256) ((short*)A_s)[i] = 0;
  for (int i = tid; i < 3 * 16 * 8; i += 256) ((short*)&A2_s[25][0][0])[i] = 0;
  for (int i = tid; i < 3 * D1; i += 256) fcw_s[i] = fc_w[i];
  if (tid < 3) fcb_s[tid] = fc_b[tid];
  __syncthreads();
  if (tid < 16) A2_s[25][tid][0] = (short)f2bf(1.f);  // k=200 bias-one

  bf16x8 wfrag[7][4];
#pragma unroll
  for (int i = 0; i < 7; ++i)
#pragma unroll
    for (int kt = 0; kt < 4; ++kt)
      wfrag[i][kt] = *(const bf16x8*)(pk_hh + ((size_t)(kt * 4 + q) * NP + (w + 4 * i) * 16 + l16) * 8);

  float c[7];
#pragma unroll
  for (int i = 0; i < 7; ++i) c[i] = 0.f;
  const size_t xgbase = (size_t)(b0 + l16) * Tt * G;

  // preload xg for t=0
  uint2 xgv[7];
#pragma unroll
  for (int i = 0; i < 7; ++i) {
    const int mt = w + 4 * i;
    if (mt < NT)
      xgv[i] = *(const uint2*)((const unsigned short*)xg + xgbase + 4 * (mt * 4 + q));
  }
  __syncthreads();

  int p = 0;
  for (int t = 0; t < Tt; ++t) {
    // prefetch xg(t+1)
    uint2 xgn[7];
    if (t < Tt - 1) {
#pragma unroll
      for (int i = 0; i < 7; ++i) {
        const int mt = w + 4 * i;
        if (mt < NT)
          xgn[i] = *(const uint2*)((const unsigned short*)xg + xgbase + (size_t)(t + 1) * G + 4 * (mt * 4 + q));
      }
    }
    bf16x8 hfrag[4];
#pragma unroll
    for (int kt = 0; kt < 4; ++kt) hfrag[kt] = *(const bf16x8*)A_s[p][kt * 4 + q][l16];
    f32x4 acc[7];
#pragma unroll
    for (int i = 0; i < 7; ++i) {
      acc[i] = (f32x4){0.f, 0.f, 0.f, 0.f};
#pragma unroll
      for (int kt = 0; kt < 4; ++kt)
        acc[i] = __builtin_amdgcn_mfma_f32_16x16x32_bf16(wfrag[i][kt], hfrag[kt], acc[i], 0, 0, 0);
    }
#pragma unroll
    for (int i = 0; i < 7; ++i) {
      const int mt = w + 4 * i;
      if (mt < NT) {
        const int j = mt * 4 + q;
        float2 f01 = __half22float2(*(const __half2*)&xgv[i].x);
        float2 f23 = __half22float2(*(const __half2*)&xgv[i].y);
        float gi = acc[i][0] + f01.x, gf = acc[i][1] + f01.y;
        float gg = acc[i][2] + f23.x, go = acc[i][3] + f23.y;
        float cc = sigm(gf) * c[i] + sigm(gi) * tanhf_(gg);
        c[i] = cc;
        float h = sigm(go) * tanhf_(cc);
        A_s[1 - p][j >> 3][l16][j & 7] = (short)f2bf(h);
        if (t == Tt - 1) hf_s[l16][j] = h;
      }
    }
#pragma unroll
    for (int i = 0; i < 7; ++i) xgv[i] = xgn[i];
    __syncthreads();
    p ^= 1;
  }

  // ---- layer-1 backward, single step at t=T-1 (h=c=0) ----
  for (int idx = tid; idx < 16 * D1; idx += 256) {
    int m = idx / D1, k = idx - m * D1;
    A2_s[k >> 3][m][k & 7] = (short)h0[((size_t)(b0 + m) * Tt + (Tt - 1)) * D1 + k];
  }
  __syncthreads();
  {
    f32x4 acc[7];
#pragma unroll
    for (int i = 0; i < 7; ++i) acc[i] = (f32x4){0.f, 0.f, 0.f, 0.f};
#pragma unroll
    for (int kt = 0; kt < 7; ++kt) {
      bf16x8 hf = *(const bf16x8*)A2_s[kt * 4 + q][l16];
#pragma unroll
      for (int i = 0; i < 7; ++i) {
        const int mt = w + 4 * i;
        bf16x8 wf = *(const bf16x8*)(pk_ihb + ((size_t)(kt * 4 + q) * NP + mt * 16 + l16) * 8);
        acc[i] = __builtin_amdgcn_mfma_f32_16x16x32_bf16(wf, hf, acc[i], 0, 0, 0);
      }
    }
#pragma unroll
    for (int i = 0; i < 7; ++i) {
      const int mt = w + 4 * i;
      if (mt < NT) {
        const int j = mt * 4 + q;
        float cc = sigm(acc[i][0]) * tanhf_(acc[i][2]);   // c_prev = 0
        hb_s[l16][j] = sigm(acc[i][3]) * tanhf_(cc);
      }
    }
  }
  __syncthreads();

  // ---- FC + softmax ----
  if (tid < 48) {
    int m = tid / 3, cls = tid - m * 3;
    float s = fcb_s[cls];
    for (int j = 0; j < H; ++j) s += fcw_s[cls * D1 + j] * hf_s[m][j];
    for (int j = 0; j < H; ++j) s += fcw_s[cls * D1 + H + j] * hb_s[m][j];
    logit_s[m][cls] = s;
  }
  __syncthreads();
  if (tid < 16) {
    float a = logit_s[tid][0], b = logit_s[tid][1], cc = logit_s[tid][2];
    float mx = fmaxf(a, fmaxf(b, cc));
    float e0 = __expf(a - mx), e1 = __expf(b - mx), e2 = __expf(cc - mx);
    float inv = 1.f / (e0 + e1 + e2);
    out[(b0 + tid) * 3 + 0] = e0 * inv;
    out[(b0 + tid) * 3 + 1] = e1 * inv;
    out[(b0 + tid) * 3 + 2] = e2 * inv;
  }
}

extern "C" void kernel_launch(void* const* d_in, const int* in_sizes, int n_in,
                              void* d_out, int out_size, void* d_ws, size_t ws_size,
                              hipStream_t stream) {
  const float* x        = (const float*)d_in[0];
  const float* w_ih_l0f = (const float*)d_in[1];
  const float* w_hh_l0f = (const float*)d_in[2];
  const float* b_ih_l0f = (const float*)d_in[3];
  const float* b_hh_l0f = (const float*)d_in[4];
  const float* w_ih_l0b = (const float*)d_in[5];
  const float* w_hh_l0b = (const float*)d_in[6];
  const float* b_ih_l0b = (const float*)d_in[7];
  const float* b_hh_l0b = (const float*)d_in[8];
  const float* w_ih_l1f = (const float*)d_in[9];
  const float* w_hh_l1f = (const float*)d_in[10];
  const float* b_ih_l1f = (const float*)d_in[11];
  const float* b_hh_l1f = (const float*)d_in[12];
  const float* w_ih_l1b = (const float*)d_in[13];
  // d_in[14] = w_hh_l1b unused (reverse dir at t=T-1 has h=0)
  const float* b_ih_l1b = (const float*)d_in[15];
  const float* b_hh_l1b = (const float*)d_in[16];
  const float* fc_w     = (const float*)d_in[17];
  const float* fc_b     = (const float*)d_in[18];

  unsigned short* h0 = (unsigned short*)d_ws;                      // 26,214,400 el
  __half* xg = (__half*)(h0 + (size_t)Bsz * Tt * D1);              // 52,428,800 el
  unsigned short* pk0f   = (unsigned short*)(xg + (size_t)Bsz * Tt * G);
  unsigned short* pk0b   = pk0f + 16 * NP * 8;
  unsigned short* pkhh1f = pk0b + 16 * NP * 8;
  unsigned short* pkih1f = pkhh1f + 16 * NP * 8;
  unsigned short* pkih1b = pkih1f + 28 * NP * 8;

  const int P16 = (16 * NP * 8 + 255) / 256, P28 = (28 * NP * 8 + 255) / 256;
  pack_aug<<<P16, 256, 0, stream>>>(w_hh_l0f, H, w_ih_l0f, IN_, b_ih_l0f, b_hh_l0f, 105, pk0f, 16);
  pack_aug<<<P16, 256, 0, stream>>>(w_hh_l0b, H, w_ih_l0b, IN_, b_ih_l0b, b_hh_l0b, 105, pk0b, 16);
  pack_aug<<<P16, 256, 0, stream>>>(w_hh_l1f, H, w_hh_l1f, 0, b_ih_l1f, b_hh_l1f, -1, pkhh1f, 16);
  pack_aug<<<P28, 256, 0, stream>>>(w_ih_l1f, D1, w_ih_l1f, 0, b_ih_l1f, b_hh_l1f, 200, pkih1f, 28);
  pack_aug<<<P28, 256, 0, stream>>>(w_ih_l1b, D1, w_ih_l1b, 0, b_ih_l1b, b_hh_l1b, 200, pkih1b, 28);

  lstm_l0<<<dim3(Bsz / 16, 2), 256, 0, stream>>>(x, pk0f, pk0b, h0);
  gemm_xg<<<(Bsz * Tt) / 64, 256, 0, stream>>>(h0, pkih1f, xg);
  lstm_l1<<<Bsz / 16, 256, 0, stream>>>(h0, pkhh1f, pkih1b, xg, fc_w, fc_b, (float*)d_out);
}

// Round 4
// 601.111 us; speedup vs baseline: 8.2733x; 1.1945x over previous
//
#include <hip/hip_runtime.h>
#include <hip/hip_fp16.h>

// LSTM_48850958024796 — R4: 8-wave blocks, spill-free weight residency,
// coalesced LDS-staged xg. Algorithm as R3: gates^T = W_aug @ [h|x|1]^T with
// gate-interleaved cols (n' = 4j+gate) so each lane owns all 4 gates of one
// (batch m=l16, hidden j=mt*4+q) element in its 4 acc regs; cell state in
// VGPRs across all 128 steps; one barrier per step.
// R4 changes (theory: R3 was VGPR-spill + uncoalesced-xg latency bound):
//  - 512 threads / 8 waves, 4 gate-tiles per wave -> wfrag 64 VGPR (was 112)
//  - NP 448->512 so tile index mt=w+8i is always in-bounds; mt<25 guards use
//  - xg double-buffered through LDS with coalesced cooperative loads
//    (row-contiguous uint2), LDS row stride 408 halves (2-way conflicts only)

typedef __attribute__((ext_vector_type(8))) short bf16x8;
typedef __attribute__((ext_vector_type(4))) float f32x4;

constexpr int Bsz = 1024, Tt = 128, IN_ = 5, H = 100, G = 400, D1 = 200;
constexpr int NP = 512;   // padded gate cols (32 MFMA tiles of 16)
constexpr int NT = 25;    // real tiles (400/16)

__device__ __forceinline__ float sigm(float x)   { return 1.f / (1.f + __expf(-x)); }
__device__ __forceinline__ float tanhf_(float x) { return 1.f - 2.f / (__expf(2.f * x) + 1.f); }
__device__ __forceinline__ unsigned short f2bf(float f) {
  unsigned u = __float_as_uint(f);
  u += 0x7fff + ((u >> 16) & 1);
  return (unsigned short)(u >> 16);
}

// packed col n' (0..511): j=n'>>2, gate=n'&3, src row = gate*100+j; j>=100 -> 0
// dst[(g*NP+n')*8+jj], k=g*8+jj: k<KA -> wA[src][k]; KA<=k<KA+KB -> wB[src][k-KA];
// k==bias_k -> b1[src]+b2[src]; else 0.
__global__ void pack_aug(const float* __restrict__ wA, int KA,
                         const float* __restrict__ wB, int KB,
                         const float* __restrict__ b1, const float* __restrict__ b2,
                         int bias_k, unsigned short* __restrict__ dst, int Kg) {
  int idx = blockIdx.x * 256 + threadIdx.x;
  int total = Kg * NP * 8;
  if (idx >= total) return;
  int jj = idx & 7, rest = idx >> 3;
  int np_ = rest % NP, g = rest / NP;
  int j = np_ >> 2, gate = np_ & 3;
  int k = g * 8 + jj;
  float v = 0.f;
  if (j < H) {
    int n = gate * H + j;
    if (k < KA) v = wA[n * KA + k];
    else if (k < KA + KB) v = wB[n * KB + (k - KA)];
    else if (k == bias_k) v = b1[n] + b2[n];
  }
  dst[idx] = f2bf(v);
}

// ---------------- layer 0 scan (grid = 64 x 2 dirs, 512 thr) ----------------
__global__ __launch_bounds__(512, 2) void lstm_l0(
    const float* __restrict__ x,
    const unsigned short* __restrict__ pk_f, const unsigned short* __restrict__ pk_b,
    unsigned short* __restrict__ h0) {
  __shared__ __align__(16) short A_s[2][16][16][8];  // [buf][kgroup][m][jj]

  const int tid = threadIdx.x;
  const int lane = tid & 63, w = tid >> 6;     // 8 waves
  const int q = lane >> 4, l16 = lane & 15;
  const int b0 = blockIdx.x * 16;
  const int dir = blockIdx.y;
  const unsigned short* pk = dir ? pk_b : pk_f;

  for (int i = tid; i < 2 * 16 * 16 * 8; i += 512) ((short*)A_s)[i] = 0;

  int mts[4]; bool tv[4];
  bf16x8 wfrag[4][4];
#pragma unroll
  for (int i = 0; i < 4; ++i) {
    int mt = w + 8 * i; mts[i] = mt; tv[i] = (mt < NT);
#pragma unroll
    for (int kt = 0; kt < 4; ++kt)
      wfrag[i][kt] = *(const bf16x8*)(pk + ((size_t)(kt * 4 + q) * NP + mt * 16 + l16) * 8);
  }
  float c[4] = {0.f, 0.f, 0.f, 0.f};
  const int xm = tid / IN_, xe = tid - xm * IN_;          // x loader (tid<80)
  const size_t hbase = (size_t)(b0 + l16) * Tt * D1 + dir * H;
  __syncthreads();
  if (tid < 16) {  // bias-one column k=105 (kg13, jj1), both buffers
    A_s[0][13][tid][1] = (short)f2bf(1.f);
    A_s[1][13][tid][1] = (short)f2bf(1.f);
  }
  if (tid < 80) {  // x(t_first) into buf 0
    int t0 = dir ? (Tt - 1) : 0;
    int k = 100 + xe;
    A_s[0][k >> 3][xm][k & 7] = (short)f2bf(x[((b0 + xm) * Tt + t0) * IN_ + xe]);
  }
  __syncthreads();

  int p = 0;
  for (int step = 0; step < Tt; ++step) {
    const int t = dir ? (Tt - 1 - step) : step;
    float xn = 0.f;
    const bool do_x = (tid < 80) && (step < Tt - 1);
    if (do_x) {
      int tn = dir ? (t - 1) : (t + 1);
      xn = x[((b0 + xm) * Tt + tn) * IN_ + xe];
    }
    bf16x8 hfrag[4];
#pragma unroll
    for (int kt = 0; kt < 4; ++kt) hfrag[kt] = *(const bf16x8*)A_s[p][kt * 4 + q][l16];
    f32x4 acc[4];
#pragma unroll
    for (int i = 0; i < 4; ++i) {
      if (!tv[i]) continue;
      acc[i] = (f32x4){0.f, 0.f, 0.f, 0.f};
#pragma unroll
      for (int kt = 0; kt < 4; ++kt)
        acc[i] = __builtin_amdgcn_mfma_f32_16x16x32_bf16(wfrag[i][kt], hfrag[kt], acc[i], 0, 0, 0);
    }
#pragma unroll
    for (int i = 0; i < 4; ++i) {
      if (!tv[i]) continue;
      const int j = mts[i] * 4 + q;
      float cc = sigm(acc[i][1]) * c[i] + sigm(acc[i][0]) * tanhf_(acc[i][2]);
      c[i] = cc;
      float h = sigm(acc[i][3]) * tanhf_(cc);
      unsigned short hb = f2bf(h);
      A_s[1 - p][j >> 3][l16][j & 7] = (short)hb;
      h0[hbase + (size_t)t * D1 + j] = hb;
    }
    if (do_x) {
      int k = 100 + xe;
      A_s[1 - p][k >> 3][xm][k & 7] = (short)f2bf(xn);
    }
    __syncthreads();
    p ^= 1;
  }
}

// ------- xg1 = h0 @ W_ih_l1f^T + bias (fp16 out, interleaved cols) ----------
__global__ __launch_bounds__(256, 2) void gemm_xg(
    const unsigned short* __restrict__ h0, const unsigned short* __restrict__ pkw,
    __half* __restrict__ xg) {
  __shared__ __align__(16) short A_s[28][64][8];  // K=224 aug (k=200 bias-one)
  __shared__ __align__(16) short B_s[28][64][8];
  const int tid = threadIdx.x;
  const int lane = tid & 63, w = tid >> 6;
  const int q = lane >> 4, l16 = lane & 15;
  const int r0 = blockIdx.x * 64;

  for (int c = tid; c < 64 * 25; c += 256) {
    int m = c / 25, g = c - m * 25;
    *(uint4*)A_s[g][m] = *(const uint4*)(h0 + (size_t)(r0 + m) * D1 + g * 8);
  }
  for (int i = tid; i < 3 * 64 * 8; i += 256) {
    int j = i & 7, gl = i >> 9;
    ((short*)&A_s[25][0][0])[i] = (short)((gl == 0 && j == 0) ? f2bf(1.f) : 0);
  }
  __syncthreads();

  for (int nb = 0; nb < 7; ++nb) {
    for (int c = tid; c < 28 * 64; c += 256) {
      int g = c >> 6, col = c & 63;
      *(uint4*)B_s[g][col] = *(const uint4*)(pkw + ((size_t)g * NP + nb * 64 + col) * 8);
    }
    __syncthreads();
    f32x4 acc[4];
#pragma unroll
    for (int nt = 0; nt < 4; ++nt) acc[nt] = (f32x4){0.f, 0.f, 0.f, 0.f};
#pragma unroll
    for (int kt = 0; kt < 7; ++kt) {
      bf16x8 af = *(const bf16x8*)A_s[kt * 4 + q][w * 16 + l16];
#pragma unroll
      for (int nt = 0; nt < 4; ++nt) {
        bf16x8 bf = *(const bf16x8*)B_s[kt * 4 + q][nt * 16 + l16];
        acc[nt] = __builtin_amdgcn_mfma_f32_16x16x32_bf16(af, bf, acc[nt], 0, 0, 0);
      }
    }
#pragma unroll
    for (int nt = 0; nt < 4; ++nt) {
      int col = nb * 64 + nt * 16 + l16;
      if (col < G) {
#pragma unroll
        for (int r = 0; r < 4; ++r) {
          int row = r0 + w * 16 + q * 4 + r;
          xg[(size_t)row * G + col] = __float2half(acc[nt][r]);
        }
      }
    }
    __syncthreads();
  }
}

// ---- layer 1: fwd scan + bwd single step + FC + softmax (512 thr) ----------
__global__ __launch_bounds__(512, 2) void lstm_l1(
    const unsigned short* __restrict__ h0,
    const unsigned short* __restrict__ pk_hh, const unsigned short* __restrict__ pk_ihb,
    const __half* __restrict__ xg,
    const float* __restrict__ fc_w, const float* __restrict__ fc_b,
    float* __restrict__ out) {
  __shared__ __align__(16) short A_s[2][16][16][8];
  __shared__ __align__(16) short A2_s[28][16][8];        // l1b: [h0(:,T-1,:)|1]
  __shared__ __align__(8) unsigned short xg_s[2][16][408];  // stride 408: 2-way max
  __shared__ float hf_s[16][H];
  __shared__ float hb_s[16][H];
  __shared__ float fcw_s[3 * D1];
  __shared__ float fcb_s[3];
  __shared__ float logit_s[16][3];

  const int tid = threadIdx.x;
  const int lane = tid & 63, w = tid >> 6;     // 8 waves
  const int q = lane >> 4, l16 = lane & 15;
  const int b0 = blockIdx.x * 16;
  const uint2* xg4 = (const uint2*)xg;         // 100 uint2 per (b,t) row

  for (int i = tid; i < 2 * 16 * 16 * 8; i += 512) ((short*)A_s)[i] = 0;
  for (int i = tid; i < 3 * 16 * 8; i += 512) {  // A2 groups 25..27: zero + bias-one
    int jj = i & 7, gl = i >> 7;
    ((short*)&A2_s[25][0][0])[i] = (short)((gl == 0 && jj == 0) ? f2bf(1.f) : 0);
  }
  for (int i = tid; i < 3 * D1; i += 512) fcw_s[i] = fc_w[i];
  if (tid < 3) fcb_s[tid] = fc_b[tid];
  for (int idx = tid; idx < 1600; idx += 512) {  // preload xg(t=0) -> buf 0
    int m = idx / 100, cu = idx - m * 100;
    *(uint2*)&xg_s[0][m][cu * 4] = xg4[((size_t)(b0 + m) * Tt) * 100 + cu];
  }

  int mts[4]; bool tv[4];
  bf16x8 wfrag[4][4];
#pragma unroll
  for (int i = 0; i < 4; ++i) {
    int mt = w + 8 * i; mts[i] = mt; tv[i] = (mt < NT);
#pragma unroll
    for (int kt = 0; kt < 4; ++kt)
      wfrag[i][kt] = *(const bf16x8*)(pk_hh + ((size_t)(kt * 4 + q) * NP + mt * 16 + l16) * 8);
  }
  float c[4] = {0.f, 0.f, 0.f, 0.f};
  __syncthreads();

  int p = 0;
  for (int t = 0; t < Tt; ++t) {
    // coalesced prefetch of xg(t+1) into regs (drained to LDS after cell phase)
    uint2 pre[4];
    if (t < Tt - 1) {
#pragma unroll
      for (int k = 0; k < 4; ++k) {
        int idx = tid + 512 * k;
        if (idx < 1600) {
          int m = idx / 100, cu = idx - m * 100;
          pre[k] = xg4[((size_t)(b0 + m) * Tt + (t + 1)) * 100 + cu];
        }
      }
    }
    bf16x8 hfrag[4];
#pragma unroll
    for (int kt = 0; kt < 4; ++kt) hfrag[kt] = *(const bf16x8*)A_s[p][kt * 4 + q][l16];
    f32x4 acc[4];
#pragma unroll
    for (int i = 0; i < 4; ++i) {
      if (!tv[i]) continue;
      acc[i] = (f32x4){0.f, 0.f, 0.f, 0.f};
#pragma unroll
      for (int kt = 0; kt < 4; ++kt)
        acc[i] = __builtin_amdgcn_mfma_f32_16x16x32_bf16(wfrag[i][kt], hfrag[kt], acc[i], 0, 0, 0);
    }
#pragma unroll
    for (int i = 0; i < 4; ++i) {
      if (!tv[i]) continue;
      const int j = mts[i] * 4 + q;
      uint2 gx = *(const uint2*)&xg_s[p][l16][4 * j];
      float2 f01 = __half22float2(*(const __half2*)&gx.x);
      float2 f23 = __half22float2(*(const __half2*)&gx.y);
      float gi = acc[i][0] + f01.x, gf = acc[i][1] + f01.y;
      float gg = acc[i][2] + f23.x, go = acc[i][3] + f23.y;
      float cc = sigm(gf) * c[i] + sigm(gi) * tanhf_(gg);
      c[i] = cc;
      float h = sigm(go) * tanhf_(cc);
      A_s[1 - p][j >> 3][l16][j & 7] = (short)f2bf(h);
      if (t == Tt - 1) hf_s[l16][j] = h;
    }
    if (t < Tt - 1) {
#pragma unroll
      for (int k = 0; k < 4; ++k) {
        int idx = tid + 512 * k;
        if (idx < 1600) {
          int m = idx / 100, cu = idx - m * 100;
          *(uint2*)&xg_s[1 - p][m][cu * 4] = pre[k];
        }
      }
    }
    __syncthreads();
    p ^= 1;
  }

  // ---- layer-1 backward, single step at t=T-1 (h=c=0) ----
  for (int idx = tid; idx < 16 * D1; idx += 512) {
    int m = idx / D1, k = idx - m * D1;
    A2_s[k >> 3][m][k & 7] = (short)h0[((size_t)(b0 + m) * Tt + (Tt - 1)) * D1 + k];
  }
  __syncthreads();
  {
    f32x4 acc[4];
#pragma unroll
    for (int i = 0; i < 4; ++i) acc[i] = (f32x4){0.f, 0.f, 0.f, 0.f};
#pragma unroll
    for (int kt = 0; kt < 7; ++kt) {
      bf16x8 hf = *(const bf16x8*)A2_s[kt * 4 + q][l16];
#pragma unroll
      for (int i = 0; i < 4; ++i) {
        if (!tv[i]) continue;
        bf16x8 wf = *(const bf16x8*)(pk_ihb + ((size_t)(kt * 4 + q) * NP + mts[i] * 16 + l16) * 8);
        acc[i] = __builtin_amdgcn_mfma_f32_16x16x32_bf16(wf, hf, acc[i], 0, 0, 0);
      }
    }
#pragma unroll
    for (int i = 0; i < 4; ++i) {
      if (!tv[i]) continue;
      const int j = mts[i] * 4 + q;
      float cc = sigm(acc[i][0]) * tanhf_(acc[i][2]);   // c_prev = 0
      hb_s[l16][j] = sigm(acc[i][3]) * tanhf_(cc);
    }
  }
  __syncthreads();

  // ---- FC + softmax ----
  if (tid < 48) {
    int m = tid / 3, cls = tid - m * 3;
    float s = fcb_s[cls];
    for (int j = 0; j < H; ++j) s += fcw_s[cls * D1 + j] * hf_s[m][j];
    for (int j = 0; j < H; ++j) s += fcw_s[cls * D1 + H + j] * hb_s[m][j];
    logit_s[m][cls] = s;
  }
  __syncthreads();
  if (tid < 16) {
    float a = logit_s[tid][0], b = logit_s[tid][1], cc = logit_s[tid][2];
    float mx = fmaxf(a, fmaxf(b, cc));
    float e0 = __expf(a - mx), e1 = __expf(b - mx), e2 = __expf(cc - mx);
    float inv = 1.f / (e0 + e1 + e2);
    out[(b0 + tid) * 3 + 0] = e0 * inv;
    out[(b0 + tid) * 3 + 1] = e1 * inv;
    out[(b0 + tid) * 3 + 2] = e2 * inv;
  }
}

extern "C" void kernel_launch(void* const* d_in, const int* in_sizes, int n_in,
                              void* d_out, int out_size, void* d_ws, size_t ws_size,
                              hipStream_t stream) {
  const float* x        = (const float*)d_in[0];
  const float* w_ih_l0f = (const float*)d_in[1];
  const float* w_hh_l0f = (const float*)d_in[2];
  const float* b_ih_l0f = (const float*)d_in[3];
  const float* b_hh_l0f = (const float*)d_in[4];
  const float* w_ih_l0b = (const float*)d_in[5];
  const float* w_hh_l0b = (const float*)d_in[6];
  const float* b_ih_l0b = (const float*)d_in[7];
  const float* b_hh_l0b = (const float*)d_in[8];
  const float* w_ih_l1f = (const float*)d_in[9];
  const float* w_hh_l1f = (const float*)d_in[10];
  const float* b_ih_l1f = (const float*)d_in[11];
  const float* b_hh_l1f = (const float*)d_in[12];
  const float* w_ih_l1b = (const float*)d_in[13];
  // d_in[14] = w_hh_l1b unused (reverse dir at t=T-1 has h=0)
  const float* b_ih_l1b = (const float*)d_in[15];
  const float* b_hh_l1b = (const float*)d_in[16];
  const float* fc_w     = (const float*)d_in[17];
  const float* fc_b     = (const float*)d_in[18];

  unsigned short* h0 = (unsigned short*)d_ws;                      // 26,214,400 el
  __half* xg = (__half*)(h0 + (size_t)Bsz * Tt * D1);              // 52,428,800 el
  unsigned short* pk0f   = (unsigned short*)(xg + (size_t)Bsz * Tt * G);
  unsigned short* pk0b   = pk0f + 16 * NP * 8;
  unsigned short* pkhh1f = pk0b + 16 * NP * 8;
  unsigned short* pkih1f = pkhh1f + 16 * NP * 8;
  unsigned short* pkih1b = pkih1f + 28 * NP * 8;

  const int P16 = (16 * NP * 8 + 255) / 256, P28 = (28 * NP * 8 + 255) / 256;
  pack_aug<<<P16, 256, 0, stream>>>(w_hh_l0f, H, w_ih_l0f, IN_, b_ih_l0f, b_hh_l0f, 105, pk0f, 16);
  pack_aug<<<P16, 256, 0, stream>>>(w_hh_l0b, H, w_ih_l0b, IN_, b_ih_l0b, b_hh_l0b, 105, pk0b, 16);
  pack_aug<<<P16, 256, 0, stream>>>(w_hh_l1f, H, w_hh_l1f, 0, b_ih_l1f, b_hh_l1f, -1, pkhh1f, 16);
  pack_aug<<<P28, 256, 0, stream>>>(w_ih_l1f, D1, w_ih_l1f, 0, b_ih_l1f, b_hh_l1f, 200, pkih1f, 28);
  pack_aug<<<P28, 256, 0, stream>>>(w_ih_l1b, D1, w_ih_l1b, 0, b_ih_l1b, b_hh_l1b, 200, pkih1b, 28);

  lstm_l0<<<dim3(Bsz / 16, 2), 512, 0, stream>>>(x, pk0f, pk0b, h0);
  gemm_xg<<<(Bsz * Tt) / 64, 256, 0, stream>>>(h0, pkih1f, xg);
  lstm_l1<<<Bsz / 16, 512, 0, stream>>>(h0, pkhh1f, pkih1b, xg, fc_w, fc_b, (float*)d_out);
}

// Round 5
// 565.130 us; speedup vs baseline: 8.8000x; 1.0637x over previous
//
#include <hip/hip_runtime.h>

// LSTM_48850958024796 — R5: fully fused layer-1 (input-proj folded into scan
// MFMA, K=320), xg buffer + gemm_xg deleted; l0 h0-stores routed through LDS
// and issued coalesced AFTER the barrier (drain overlaps next step).
// Algorithm (R3-proven): gates^T = W_aug(A) @ [h|inputs|1]^T(B), cols packed
// gate-interleaved (n'=4j+gate) so lane(q,l16) tile mt owns all 4 gates of
// (batch m=l16, hidden j=mt*4+q) in acc[0..3]; c state in VGPRs; 1 barrier/step.
// l1 K layout: k0..99=h1 | k100..103=0 | k104..303=h0f,h0b | k304=1 | pad. The
// l1-backward tail reuses the final staged buffer with pk1b (zeros over k<104).

typedef __attribute__((ext_vector_type(8))) short bf16x8;
typedef __attribute__((ext_vector_type(4))) float f32x4;

constexpr int Bsz = 1024, Tt = 128, IN_ = 5, H = 100, G = 400, D1 = 200;
constexpr int NP = 512;   // padded gate cols (32 tiles of 16)
constexpr int NT = 25;    // real tiles (400/16)

__device__ __forceinline__ float sigm(float x)   { return 1.f / (1.f + __expf(-x)); }
__device__ __forceinline__ float tanhf_(float x) { return 1.f - 2.f / (__expf(2.f * x) + 1.f); }
__device__ __forceinline__ unsigned short f2bf(float f) {
  unsigned u = __float_as_uint(f);
  u += 0x7fff + ((u >> 16) & 1);
  return (unsigned short)(u >> 16);
}

// packed col n' (0..511): j=n'>>2, gate=n'&3, src row n = gate*100+j; j>=100->0
// dst[(g*NP+n')*8+jj], k=g*8+jj: k<KA -> wA[n][k]; kbo<=k<kbo+KB -> wB[n][k-kbo];
// k==bias_k -> b1[n]+b2[n]; else 0.
__global__ void pack_aug(const float* __restrict__ wA, int KA,
                         const float* __restrict__ wB, int KB, int kbo,
                         const float* __restrict__ b1, const float* __restrict__ b2,
                         int bias_k, unsigned short* __restrict__ dst, int Kg) {
  int idx = blockIdx.x * 256 + threadIdx.x;
  if (idx >= Kg * NP * 8) return;
  int jj = idx & 7, rest = idx >> 3;
  int np_ = rest % NP, g = rest / NP;
  int j = np_ >> 2, gate = np_ & 3;
  int k = g * 8 + jj;
  float v = 0.f;
  if (j < H) {
    int n = gate * H + j;
    if (k < KA) v = wA[n * KA + k];
    else if (k >= kbo && k < kbo + KB) v = wB[n * KB + (k - kbo)];
    else if (k == bias_k) v = b1[n] + b2[n];
  }
  dst[idx] = f2bf(v);
}

// ---------------- layer 0 scan (grid = 64 x 2 dirs, 512 thr) ----------------
__global__ __launch_bounds__(512, 2) void lstm_l0(
    const float* __restrict__ x,
    const unsigned short* __restrict__ pk_f, const unsigned short* __restrict__ pk_b,
    unsigned short* __restrict__ h0) {
  __shared__ __align__(16) short A_s[2][16][16][8];  // [buf][kgroup][m][jj], K=128

  const int tid = threadIdx.x;
  const int lane = tid & 63, w = tid >> 6;
  const int q = lane >> 4, l16 = lane & 15;
  const int b0 = blockIdx.x * 16;
  const int dir = blockIdx.y;
  const unsigned short* pk = dir ? pk_b : pk_f;

  for (int i = tid; i < 2 * 16 * 16 * 8; i += 512) ((short*)A_s)[i] = 0;

  int mts[4]; bool tv[4];
  bf16x8 wfrag[4][4];
#pragma unroll
  for (int i = 0; i < 4; ++i) {
    int mt = w + 8 * i; mts[i] = mt; tv[i] = (mt < NT);
#pragma unroll
    for (int kt = 0; kt < 4; ++kt)
      wfrag[i][kt] = *(const bf16x8*)(pk + ((size_t)(kt * 4 + q) * NP + mt * 16 + l16) * 8);
  }
  float c[4] = {0.f, 0.f, 0.f, 0.f};
  const int xm = tid / IN_, xe = tid - xm * IN_;  // x loader (tid<80)
  const int sm = tid & 15, scu = tid >> 4;        // h0 store mapping (tid<400)
  __syncthreads();
  if (tid < 16) {  // bias-one column k=105 (kg13, jj1), both buffers
    A_s[0][13][tid][1] = (short)f2bf(1.f);
    A_s[1][13][tid][1] = (short)f2bf(1.f);
  }
  if (tid < 80) {  // x(t_first) into buf 0
    int t0 = dir ? (Tt - 1) : 0;
    int k = 100 + xe;
    A_s[0][k >> 3][xm][k & 7] = (short)f2bf(x[((b0 + xm) * Tt + t0) * IN_ + xe]);
  }
  __syncthreads();

  int p = 0;
  for (int step = 0; step < Tt; ++step) {
    const int t = dir ? (Tt - 1 - step) : step;
    // coalesced store of h(prev) from the buffer being consumed; drains at the
    // NEXT barrier, fully overlapped with this step's compute
    if (step > 0 && tid < 400) {
      int tp = dir ? (t + 1) : (t - 1);
      uint2 hv = *(const uint2*)&A_s[p][scu >> 1][sm][(scu & 1) * 4];
      *(uint2*)(h0 + ((size_t)(b0 + sm) * Tt + tp) * D1 + dir * H + scu * 4) = hv;
    }
    float xn = 0.f;
    const bool do_x = (tid < 80) && (step < Tt - 1);
    if (do_x) {
      int tn = dir ? (t - 1) : (t + 1);
      xn = x[((b0 + xm) * Tt + tn) * IN_ + xe];
    }
    bf16x8 hfrag[4];
#pragma unroll
    for (int kt = 0; kt < 4; ++kt) hfrag[kt] = *(const bf16x8*)A_s[p][kt * 4 + q][l16];
    f32x4 acc[4];
#pragma unroll
    for (int i = 0; i < 4; ++i) {
      if (!tv[i]) continue;
      acc[i] = (f32x4){0.f, 0.f, 0.f, 0.f};
#pragma unroll
      for (int kt = 0; kt < 4; ++kt)
        acc[i] = __builtin_amdgcn_mfma_f32_16x16x32_bf16(wfrag[i][kt], hfrag[kt], acc[i], 0, 0, 0);
    }
#pragma unroll
    for (int i = 0; i < 4; ++i) {
      if (!tv[i]) continue;
      const int j = mts[i] * 4 + q;
      float cc = sigm(acc[i][1]) * c[i] + sigm(acc[i][0]) * tanhf_(acc[i][2]);
      c[i] = cc;
      float h = sigm(acc[i][3]) * tanhf_(cc);
      A_s[1 - p][j >> 3][l16][j & 7] = (short)f2bf(h);
    }
    if (do_x) {
      int k = 100 + xe;
      A_s[1 - p][k >> 3][xm][k & 7] = (short)f2bf(xn);
    }
    __syncthreads();
    p ^= 1;
  }
  // final h store (t = last)
  if (tid < 400) {
    int tl = dir ? 0 : (Tt - 1);
    uint2 hv = *(const uint2*)&A_s[p][scu >> 1][sm][(scu & 1) * 4];
    *(uint2*)(h0 + ((size_t)(b0 + sm) * Tt + tl) * D1 + dir * H + scu * 4) = hv;
  }
}

// ---- layer 1 fused: fwd scan (K=320) + bwd single step + FC + softmax ------
__global__ __launch_bounds__(512, 2) void lstm_l1(
    const unsigned short* __restrict__ h0,
    const unsigned short* __restrict__ pk1f, const unsigned short* __restrict__ pk1b,
    const float* __restrict__ fc_w, const float* __restrict__ fc_b,
    float* __restrict__ out) {
  __shared__ __align__(16) short B_s[2][40][16][8];  // [buf][kgroup][m][jj]
  __shared__ float hf_s[16][H];
  __shared__ float hb_s[16][H];
  __shared__ float fcw_s[3 * D1];
  __shared__ float fcb_s[3];
  __shared__ float logit_s[16][3];

  const int tid = threadIdx.x;
  const int lane = tid & 63, w = tid >> 6;
  const int q = lane >> 4, l16 = lane & 15;
  const int b0 = blockIdx.x * 16;
  const int sm = tid & 15, scu = tid >> 4;   // h0 staging mapping (tid<400)

  for (int i = tid; i < 2 * 40 * 16 * 8; i += 512) ((short*)B_s)[i] = 0;
  for (int i = tid; i < 3 * D1; i += 512) fcw_s[i] = fc_w[i];
  if (tid < 3) fcb_s[tid] = fc_b[tid];

  int mts[4]; bool tv[4];
  bf16x8 wfrag[4][10];
#pragma unroll
  for (int i = 0; i < 4; ++i) {
    int mt = w + 8 * i; mts[i] = mt; tv[i] = (mt < NT);
#pragma unroll
    for (int kt = 0; kt < 10; ++kt)
      wfrag[i][kt] = *(const bf16x8*)(pk1f + ((size_t)(kt * 4 + q) * NP + mt * 16 + l16) * 8);
  }
  float c[4] = {0.f, 0.f, 0.f, 0.f};
  __syncthreads();
  if (tid < 32) {  // bias-one column k=304 (kg38, jj0), both buffers
    B_s[tid >> 4][38][tid & 15][0] = (short)f2bf(1.f);
  }
  if (tid < 400) {  // stage h0(t=0) -> buf 0 (k=104..303, kg 13..37)
    *(uint4*)&B_s[0][13 + scu][sm][0] =
        *(const uint4*)(h0 + ((size_t)(b0 + sm) * Tt + 0) * D1 + scu * 8);
  }
  __syncthreads();

  int p = 0;
  for (int t = 0; t < Tt; ++t) {
    uint4 pre;
    const bool do_s = (tid < 400) && (t < Tt - 1);
    if (do_s)
      pre = *(const uint4*)(h0 + ((size_t)(b0 + sm) * Tt + (t + 1)) * D1 + scu * 8);
    f32x4 acc[4];
#pragma unroll
    for (int i = 0; i < 4; ++i) acc[i] = (f32x4){0.f, 0.f, 0.f, 0.f};
#pragma unroll
    for (int kt = 0; kt < 10; ++kt) {
      bf16x8 hf = *(const bf16x8*)B_s[p][kt * 4 + q][l16];
#pragma unroll
      for (int i = 0; i < 4; ++i) {
        if (!tv[i]) continue;
        acc[i] = __builtin_amdgcn_mfma_f32_16x16x32_bf16(wfrag[i][kt], hf, acc[i], 0, 0, 0);
      }
    }
#pragma unroll
    for (int i = 0; i < 4; ++i) {
      if (!tv[i]) continue;
      const int j = mts[i] * 4 + q;
      float cc = sigm(acc[i][1]) * c[i] + sigm(acc[i][0]) * tanhf_(acc[i][2]);
      c[i] = cc;
      float h = sigm(acc[i][3]) * tanhf_(cc);
      B_s[1 - p][j >> 3][l16][j & 7] = (short)f2bf(h);
      if (t == Tt - 1) hf_s[l16][j] = h;
    }
    if (do_s) *(uint4*)&B_s[1 - p][13 + scu][sm][0] = pre;
    __syncthreads();
    p ^= 1;
  }

  // ---- layer-1 backward single step at t=T-1 (h=c=0): reuse the step-127
  // buffer (1-p): holds [h1(126)|h0(127)|1]; pk1b is zero over k<104 so the
  // stale h1 part contributes nothing.
  {
    const int bp = 1 - p;
    f32x4 acc[4];
#pragma unroll
    for (int i = 0; i < 4; ++i) acc[i] = (f32x4){0.f, 0.f, 0.f, 0.f};
#pragma unroll
    for (int kt = 0; kt < 10; ++kt) {
      bf16x8 hf = *(const bf16x8*)B_s[bp][kt * 4 + q][l16];
#pragma unroll
      for (int i = 0; i < 4; ++i) {
        if (!tv[i]) continue;
        bf16x8 wf = *(const bf16x8*)(pk1b + ((size_t)(kt * 4 + q) * NP + mts[i] * 16 + l16) * 8);
        acc[i] = __builtin_amdgcn_mfma_f32_16x16x32_bf16(wf, hf, acc[i], 0, 0, 0);
      }
    }
#pragma unroll
    for (int i = 0; i < 4; ++i) {
      if (!tv[i]) continue;
      const int j = mts[i] * 4 + q;
      float cc = sigm(acc[i][0]) * tanhf_(acc[i][2]);   // c_prev = 0
      hb_s[l16][j] = sigm(acc[i][3]) * tanhf_(cc);
    }
  }
  __syncthreads();

  // ---- FC (3x200) + softmax ----
  if (tid < 48) {
    int m = tid / 3, cls = tid - m * 3;
    float s = fcb_s[cls];
    for (int j = 0; j < H; ++j) s += fcw_s[cls * D1 + j] * hf_s[m][j];
    for (int j = 0; j < H; ++j) s += fcw_s[cls * D1 + H + j] * hb_s[m][j];
    logit_s[m][cls] = s;
  }
  __syncthreads();
  if (tid < 16) {
    float a = logit_s[tid][0], b = logit_s[tid][1], cc = logit_s[tid][2];
    float mx = fmaxf(a, fmaxf(b, cc));
    float e0 = __expf(a - mx), e1 = __expf(b - mx), e2 = __expf(cc - mx);
    float inv = 1.f / (e0 + e1 + e2);
    out[(b0 + tid) * 3 + 0] = e0 * inv;
    out[(b0 + tid) * 3 + 1] = e1 * inv;
    out[(b0 + tid) * 3 + 2] = e2 * inv;
  }
}

extern "C" void kernel_launch(void* const* d_in, const int* in_sizes, int n_in,
                              void* d_out, int out_size, void* d_ws, size_t ws_size,
                              hipStream_t stream) {
  const float* x        = (const float*)d_in[0];
  const float* w_ih_l0f = (const float*)d_in[1];
  const float* w_hh_l0f = (const float*)d_in[2];
  const float* b_ih_l0f = (const float*)d_in[3];
  const float* b_hh_l0f = (const float*)d_in[4];
  const float* w_ih_l0b = (const float*)d_in[5];
  const float* w_hh_l0b = (const float*)d_in[6];
  const float* b_ih_l0b = (const float*)d_in[7];
  const float* b_hh_l0b = (const float*)d_in[8];
  const float* w_ih_l1f = (const float*)d_in[9];
  const float* w_hh_l1f = (const float*)d_in[10];
  const float* b_ih_l1f = (const float*)d_in[11];
  const float* b_hh_l1f = (const float*)d_in[12];
  const float* w_ih_l1b = (const float*)d_in[13];
  // d_in[14] = w_hh_l1b unused (reverse dir at t=T-1 has h=0)
  const float* b_ih_l1b = (const float*)d_in[15];
  const float* b_hh_l1b = (const float*)d_in[16];
  const float* fc_w     = (const float*)d_in[17];
  const float* fc_b     = (const float*)d_in[18];

  unsigned short* h0   = (unsigned short*)d_ws;        // 26,214,400 halves
  unsigned short* pk0f = h0 + (size_t)Bsz * Tt * D1;   // 16*512*8
  unsigned short* pk0b = pk0f + 16 * NP * 8;
  unsigned short* pk1f = pk0b + 16 * NP * 8;           // 40*512*8
  unsigned short* pk1b = pk1f + 40 * NP * 8;

  const int P16 = (16 * NP * 8 + 255) / 256, P40 = (40 * NP * 8 + 255) / 256;
  pack_aug<<<P16, 256, 0, stream>>>(w_hh_l0f, 100, w_ih_l0f, 5, 100,
                                    b_ih_l0f, b_hh_l0f, 105, pk0f, 16);
  pack_aug<<<P16, 256, 0, stream>>>(w_hh_l0b, 100, w_ih_l0b, 5, 100,
                                    b_ih_l0b, b_hh_l0b, 105, pk0b, 16);
  pack_aug<<<P40, 256, 0, stream>>>(w_hh_l1f, 100, w_ih_l1f, 200, 104,
                                    b_ih_l1f, b_hh_l1f, 304, pk1f, 40);
  pack_aug<<<P40, 256, 0, stream>>>(w_ih_l1b, 0, w_ih_l1b, 200, 104,
                                    b_ih_l1b, b_hh_l1b, 304, pk1b, 40);

  lstm_l0<<<dim3(Bsz / 16, 2), 512, 0, stream>>>(x, pk0f, pk0b, h0);
  lstm_l1<<<Bsz / 16, 512, 0, stream>>>(h0, pk1f, pk1b, fc_w, fc_b, (float*)d_out);
}